// Round 1
// baseline (48.537 us; speedup 1.0000x reference)
//
#include <hip/hip_runtime.h>

#define DIM 1024
#define HEADS 16
#define HEAD_DIM 64
#define BATCH 2
#define SEQ 2048

// ws float layout:
// [0,1024)    qa = w_in @ wq   (column d: sum_j w_in[j]*wq[j][d])
// [1024,2048) qb = b_in @ wq
// [2048,3072) ka = w_in @ wk
// [3072,4096) va = w_in @ wv
// [4096,5120) vb = b_in @ wv
// [5120,6144) u  = wo @ wf     (row d: sum_e wo[d][e]*wf[e])
// [6144,6160) A[h] = qa_h . ka_h
// [6160,6176) C[h] = qb_h . ka_h
// [6176,6192) g[h] = va_h . u_h
// [6192]      c0   = vb.u + bo.wf + bf

__global__ void precompute_cols(const float* __restrict__ w_in,
                                const float* __restrict__ b_in,
                                const float* __restrict__ wq,
                                const float* __restrict__ wk,
                                const float* __restrict__ wv,
                                float* __restrict__ ws) {
    // grid 64: (blockIdx&3) selects d-range of 256, (blockIdx>>2) selects j-chunk of 64
    int d  = (blockIdx.x & 3) * 256 + threadIdx.x;
    int j0 = (blockIdx.x >> 2) * 64;
    float qa = 0.f, qb = 0.f, ka = 0.f, va = 0.f, vb = 0.f;
    for (int j = j0; j < j0 + 64; ++j) {
        float wi = w_in[j], bi = b_in[j];
        float cq = wq[j * DIM + d];
        float ck = wk[j * DIM + d];
        float cv = wv[j * DIM + d];
        qa += wi * cq;
        qb += bi * cq;
        ka += wi * ck;
        va += wi * cv;
        vb += bi * cv;
    }
    atomicAdd(&ws[d], qa);
    atomicAdd(&ws[DIM + d], qb);
    atomicAdd(&ws[2 * DIM + d], ka);
    atomicAdd(&ws[3 * DIM + d], va);
    atomicAdd(&ws[4 * DIM + d], vb);
}

__global__ void precompute_u(const float* __restrict__ wo,
                             const float* __restrict__ wf,
                             float* __restrict__ ws) {
    // one wave per row of wo; grid 256 x 256 threads = 1024 waves
    int wave = threadIdx.x >> 6, lane = threadIdx.x & 63;
    int row = blockIdx.x * 4 + wave;
    float s = 0.f;
    for (int e = lane; e < DIM; e += 64) s += wo[row * DIM + e] * wf[e];
    for (int off = 32; off; off >>= 1) s += __shfl_down(s, off);
    if (lane == 0) ws[5 * DIM + row] = s;
}

__global__ void precompute_combine(const float* __restrict__ bo,
                                   const float* __restrict__ wf,
                                   const float* __restrict__ bf,
                                   float* __restrict__ ws) {
    // single block, 1024 threads; wave h == head h (64 contiguous d per head)
    int d = threadIdx.x;
    int h = d >> 6, lane = d & 63;
    float qa = ws[d], qb = ws[DIM + d], ka = ws[2 * DIM + d];
    float va = ws[3 * DIM + d], vb = ws[4 * DIM + d], u = ws[5 * DIM + d];
    float pA = qa * ka;
    float pC = qb * ka;
    float pG = va * u;
    float pc = vb * u + bo[d] * wf[d];
    for (int off = 32; off; off >>= 1) {
        pA += __shfl_down(pA, off);
        pC += __shfl_down(pC, off);
        pG += __shfl_down(pG, off);
        pc += __shfl_down(pc, off);
    }
    __shared__ float red[16];
    if (lane == 0) {
        ws[6 * DIM + h]      = pA;
        ws[6 * DIM + 16 + h] = pC;
        ws[6 * DIM + 32 + h] = pG;
        red[h] = pc;
    }
    __syncthreads();
    if (d == 0) {
        float c0 = bf[0];
        #pragma unroll
        for (int i = 0; i < 16; ++i) c0 += red[i];
        ws[6 * DIM + 48] = c0;
    }
}

__global__ __launch_bounds__(1024) void attn_main(const float* __restrict__ x,
                                                  const float* __restrict__ ws,
                                                  float* __restrict__ out) {
    // one block per (b,q); 16 waves = 16 heads
    int bid = blockIdx.x;
    int b = bid >> 11;       // S = 2048
    int q = bid & (SEQ - 1);
    int tid = threadIdx.x;
    int h = tid >> 6, lane = tid & 63;

    __shared__ float xs[SEQ];
    __shared__ float part[HEADS];

    const float* xb = x + b * SEQ;
    for (int i = tid; i <= q; i += 1024) xs[i] = xb[i];
    __syncthreads();

    float xq = xs[q];
    float A  = ws[6 * DIM + h];
    float C  = ws[6 * DIM + 16 + h];
    float g  = ws[6 * DIM + 32 + h];
    float c0 = ws[6 * DIM + 48];
    float alpha = 0.125f * (A * xq + C);   // HEAD_DIM^-0.5 = 1/8

    // logits are alpha * x_k; constants cancel in softmax. |alpha*x| << 88 so no
    // max-subtraction needed for fp32 exp.
    float num = 0.f, den = 0.f;
    for (int k = lane; k <= q; k += 64) {
        float xk = xs[k];
        float e = __expf(alpha * xk);
        den += e;
        num += e * xk;
    }
    for (int off = 32; off; off >>= 1) {
        num += __shfl_down(num, off);
        den += __shfl_down(den, off);
    }
    if (lane == 0) part[h] = g * (num / den);
    __syncthreads();
    if (tid == 0) {
        float r = c0;
        #pragma unroll
        for (int i = 0; i < HEADS; ++i) r += part[i];
        out[b * SEQ + q] = r;
    }
}

extern "C" void kernel_launch(void* const* d_in, const int* in_sizes, int n_in,
                              void* d_out, int out_size, void* d_ws, size_t ws_size,
                              hipStream_t stream) {
    const float* x    = (const float*)d_in[0];
    const float* w_in = (const float*)d_in[1];
    const float* b_in = (const float*)d_in[2];
    const float* wq   = (const float*)d_in[3];
    const float* wk   = (const float*)d_in[4];
    const float* wv   = (const float*)d_in[5];
    const float* wo   = (const float*)d_in[6];
    const float* bo   = (const float*)d_in[7];
    const float* wf   = (const float*)d_in[8];
    const float* bf   = (const float*)d_in[9];
    float* out = (float*)d_out;
    float* ws  = (float*)d_ws;

    // zero only the atomicAdd targets (qa..vb)
    hipMemsetAsync(ws, 0, 5 * DIM * sizeof(float), stream);
    precompute_cols<<<64, 256, 0, stream>>>(w_in, b_in, wq, wk, wv, ws);
    precompute_u<<<256, 256, 0, stream>>>(wo, wf, ws);
    precompute_combine<<<1, 1024, 0, stream>>>(bo, wf, bf, ws);
    attn_main<<<BATCH * SEQ, 1024, 0, stream>>>(x, ws, out);
}

// Round 2
// 39.116 us; speedup vs baseline: 1.2409x; 1.2409x over previous
//
#include <hip/hip_runtime.h>

#define DIM 1024
#define HEADS 16
#define HEAD_DIM 64
#define BATCH 2
#define SEQ 2048

// ws float layout:
// [5120,6144) u[row] = wo @ wf
// [6144,6160) A[h] = qa_h . ka_h
// [6160,6176) C[h] = qb_h . ka_h
// [6176,6192) g[h] = va_h . u_h
// [6192]      c0   = vb.u + bo.wf + bf
// [8192, 8192+32*5*1024) partials P[c][w][d]: w in {qa,qb,ka,va,vb}
#define WS_U    5120
#define WS_A    6144
#define WS_C    6160
#define WS_G    6176
#define WS_C0   6192
#define WS_PART 8192

// grid 384: blocks [0,128) = column partials of wq/wk/wv; [128,384) = rows of wo@wf
__global__ __launch_bounds__(256) void precompute_part(
        const float* __restrict__ w_in, const float* __restrict__ b_in,
        const float* __restrict__ wq,   const float* __restrict__ wk,
        const float* __restrict__ wv,   const float* __restrict__ wo,
        const float* __restrict__ wf,   float* __restrict__ ws) {
    int bid = blockIdx.x;
    if (bid < 128) {
        int d  = (bid & 3) * 256 + threadIdx.x;   // d-group
        int c  = bid >> 2;                        // j-chunk 0..31
        int j0 = c * 32;
        float qa = 0.f, qb = 0.f, ka = 0.f, va = 0.f, vb = 0.f;
        #pragma unroll 4
        for (int j = j0; j < j0 + 32; ++j) {
            float wi = w_in[j], bi = b_in[j];
            float cq = wq[j * DIM + d];
            float ck = wk[j * DIM + d];
            float cv = wv[j * DIM + d];
            qa += wi * cq;
            qb += bi * cq;
            ka += wi * ck;
            va += wi * cv;
            vb += bi * cv;
        }
        int base = WS_PART + c * 5 * DIM + d;
        ws[base]           = qa;
        ws[base + DIM]     = qb;
        ws[base + 2 * DIM] = ka;
        ws[base + 3 * DIM] = va;
        ws[base + 4 * DIM] = vb;
    } else {
        // one wave per row of wo
        int wave = threadIdx.x >> 6, lane = threadIdx.x & 63;
        int row = (bid - 128) * 4 + wave;
        float s = 0.f;
        #pragma unroll 4
        for (int e = lane; e < DIM; e += 64) s += wo[row * DIM + e] * wf[e];
        for (int off = 32; off; off >>= 1) s += __shfl_down(s, off);
        if (lane == 0) ws[WS_U + row] = s;
    }
}

__global__ __launch_bounds__(1024) void precompute_combine(
        const float* __restrict__ bo, const float* __restrict__ wf,
        const float* __restrict__ bf, float* __restrict__ ws) {
    int d = threadIdx.x;
    int h = d >> 6, lane = d & 63;
    float qa = 0.f, qb = 0.f, ka = 0.f, va = 0.f, vb = 0.f;
    for (int c = 0; c < 32; ++c) {
        int base = WS_PART + c * 5 * DIM + d;
        qa += ws[base];
        qb += ws[base + DIM];
        ka += ws[base + 2 * DIM];
        va += ws[base + 3 * DIM];
        vb += ws[base + 4 * DIM];
    }
    float u = ws[WS_U + d];
    float pA = qa * ka;
    float pC = qb * ka;
    float pG = va * u;
    float pc = vb * u + bo[d] * wf[d];
    for (int off = 32; off; off >>= 1) {
        pA += __shfl_down(pA, off);
        pC += __shfl_down(pC, off);
        pG += __shfl_down(pG, off);
        pc += __shfl_down(pc, off);
    }
    __shared__ float red[16];
    if (lane == 0) {
        ws[WS_A + h] = pA;
        ws[WS_C + h] = pC;
        ws[WS_G + h] = pG;
        red[h] = pc;
    }
    __syncthreads();
    if (d == 0) {
        float c0 = bf[0];
        #pragma unroll
        for (int i = 0; i < 16; ++i) c0 += red[i];
        ws[WS_C0] = c0;
    }
}

// one block per (b,q); 4 waves, each wave owns 4 heads (one ds_read feeds 4 exps)
__global__ __launch_bounds__(256) void attn_main(const float* __restrict__ x,
                                                 const float* __restrict__ ws,
                                                 float* __restrict__ out) {
    int bid = blockIdx.x;
    int b = bid >> 11;               // SEQ = 2048
    int q = (SEQ - 1) - (bid & (SEQ - 1));   // big-q blocks dispatch first
    int tid = threadIdx.x;
    int w = tid >> 6, lane = tid & 63;

    __shared__ float xs[SEQ];
    __shared__ float part[HEADS];

    const float* xb = x + b * SEQ;
    for (int i = tid; i <= q; i += 256) xs[i] = xb[i];
    __syncthreads();

    float xq = xs[q];
    int h0 = w * 4;
    float a0 = 0.125f * (ws[WS_A + h0 + 0] * xq + ws[WS_C + h0 + 0]);
    float a1 = 0.125f * (ws[WS_A + h0 + 1] * xq + ws[WS_C + h0 + 1]);
    float a2 = 0.125f * (ws[WS_A + h0 + 2] * xq + ws[WS_C + h0 + 2]);
    float a3 = 0.125f * (ws[WS_A + h0 + 3] * xq + ws[WS_C + h0 + 3]);

    // logits are alpha*x_k; additive constants cancel in softmax. |alpha*x| << 88,
    // no max-subtraction needed in fp32.
    float n0 = 0.f, n1 = 0.f, n2 = 0.f, n3 = 0.f;
    float d0 = 0.f, d1 = 0.f, d2 = 0.f, d3 = 0.f;
    for (int k = lane; k <= q; k += 64) {
        float xk = xs[k];
        float e0 = __expf(a0 * xk);
        float e1 = __expf(a1 * xk);
        float e2 = __expf(a2 * xk);
        float e3 = __expf(a3 * xk);
        d0 += e0; n0 += e0 * xk;
        d1 += e1; n1 += e1 * xk;
        d2 += e2; n2 += e2 * xk;
        d3 += e3; n3 += e3 * xk;
    }
    for (int off = 32; off; off >>= 1) {
        n0 += __shfl_down(n0, off); d0 += __shfl_down(d0, off);
        n1 += __shfl_down(n1, off); d1 += __shfl_down(d1, off);
        n2 += __shfl_down(n2, off); d2 += __shfl_down(d2, off);
        n3 += __shfl_down(n3, off); d3 += __shfl_down(d3, off);
    }
    if (lane == 0) {
        part[h0 + 0] = ws[WS_G + h0 + 0] * (n0 / d0);
        part[h0 + 1] = ws[WS_G + h0 + 1] * (n1 / d1);
        part[h0 + 2] = ws[WS_G + h0 + 2] * (n2 / d2);
        part[h0 + 3] = ws[WS_G + h0 + 3] * (n3 / d3);
    }
    __syncthreads();
    if (tid == 0) {
        float r = ws[WS_C0];
        #pragma unroll
        for (int i = 0; i < HEADS; ++i) r += part[i];
        out[b * SEQ + q] = r;
    }
}

extern "C" void kernel_launch(void* const* d_in, const int* in_sizes, int n_in,
                              void* d_out, int out_size, void* d_ws, size_t ws_size,
                              hipStream_t stream) {
    const float* x    = (const float*)d_in[0];
    const float* w_in = (const float*)d_in[1];
    const float* b_in = (const float*)d_in[2];
    const float* wq   = (const float*)d_in[3];
    const float* wk   = (const float*)d_in[4];
    const float* wv   = (const float*)d_in[5];
    const float* wo   = (const float*)d_in[6];
    const float* bo   = (const float*)d_in[7];
    const float* wf   = (const float*)d_in[8];
    const float* bf   = (const float*)d_in[9];
    float* out = (float*)d_out;
    float* ws  = (float*)d_ws;

    precompute_part<<<384, 256, 0, stream>>>(w_in, b_in, wq, wk, wv, wo, wf, ws);
    precompute_combine<<<1, 1024, 0, stream>>>(bo, wf, bf, ws);
    attn_main<<<BATCH * SEQ, 256, 0, stream>>>(x, ws, out);
}